// Round 2
// baseline (537.586 us; speedup 1.0000x reference)
//
#include <hip/hip_runtime.h>
#include <stdint.h>

typedef __attribute__((ext_vector_type(4))) float f32x4;
typedef __attribute__((ext_vector_type(8))) short s16x8;
typedef __attribute__((ext_vector_type(8))) unsigned short u16x8;

#define MFMA16(a, b, c) __builtin_amdgcn_mfma_f32_16x16x32_bf16((a), (b), (c), 0, 0, 0)

__device__ __forceinline__ unsigned short f2bf(float f) {
  unsigned int u = __float_as_uint(f);
  u += 0x7fffu + ((u >> 16) & 1u);
  return (unsigned short)(u >> 16);
}

__device__ __forceinline__ void gll16(const unsigned short* g, unsigned short* l) {
  __builtin_amdgcn_global_load_lds((__attribute__((address_space(1))) void*)g,
                                   (__attribute__((address_space(3))) void*)l, 16, 0, 0);
}

// ---------------- fp32 -> bf16 conversion (q,k,v,Wq,Wk,Wv,Wo) ----------------
__global__ __launch_bounds__(256) void cvt_kernel(
    const float* __restrict__ q, const float* __restrict__ k, const float* __restrict__ v,
    const float* __restrict__ Wq, const float* __restrict__ Wk,
    const float* __restrict__ Wv, const float* __restrict__ Wo,
    unsigned short* __restrict__ dst) {
  const size_t i = ((size_t)blockIdx.x * 256 + threadIdx.x) * 8;
  const size_t M1 = 4194304, W1 = 1048576;
  const float* src;
  if (i < M1) src = q + i;
  else if (i < 2 * M1) src = k + (i - M1);
  else if (i < 3 * M1) src = v + (i - 2 * M1);
  else {
    const size_t j = i - 3 * M1;
    src = (j < W1) ? Wq + j : (j < 2 * W1) ? Wk + (j - W1)
        : (j < 3 * W1) ? Wv + (j - 2 * W1) : Wo + (j - 3 * W1);
  }
  f32x4 a = *(const f32x4*)src;
  f32x4 c2 = *(const f32x4*)(src + 4);
  u16x8 o;
  o[0] = f2bf(a[0]);  o[1] = f2bf(a[1]);  o[2] = f2bf(a[2]);  o[3] = f2bf(a[3]);
  o[4] = f2bf(c2[0]); o[5] = f2bf(c2[1]); o[6] = f2bf(c2[2]); o[7] = f2bf(c2[3]);
  *(u16x8*)(dst + i) = o;
}

// ---------------- shared 128x128x(K=1024) bf16 GEMM core (m97-style) ----------------
// LDS chunk-permuted source swizzle: chunk cc of row goes to LDS slot cc ^ ((row>>1)&3)
// -> ds_read_b128 frag reads are 2-way (free) instead of 8-way bank-conflicted.
#define GEMM_PROLOG()                                                          \
  __shared__ unsigned short As[4096], Bs[4096];                                \
  const int lane = threadIdx.x & 63, wid = threadIdx.x >> 6;                   \
  const int g = lane >> 4, ln = lane & 15;                                     \
  const int wr = wid >> 1, wc = wid & 1;                                       \
  const int mt = blockIdx.y, nt = blockIdx.x;                                  \
  f32x4 acc[4][4];                                                             \
  { f32x4 z = {0.f, 0.f, 0.f, 0.f};                                            \
    _Pragma("unroll") for (int a_ = 0; a_ < 4; ++a_)                           \
      _Pragma("unroll") for (int b_ = 0; b_ < 4; ++b_) acc[a_][b_] = z; }      \
  const int c0 = wid * 64 + lane;                                              \
  const int row0 = c0 >> 2, cg0 = (c0 & 3) ^ ((row0 >> 1) & 3);                \
  const int c1 = 256 + c0;                                                     \
  const int row1 = c1 >> 2, cg1 = (c1 & 3) ^ ((row1 >> 1) & 3);

#define GEMM_KLOOP(Ag, Bg)                                                     \
  for (int kb = 0; kb < 32; ++kb) {                                            \
    gll16(Ag + (size_t)(mt * 128 + row0) * 1024 + kb * 32 + cg0 * 8,           \
          As + (size_t)(wid * 64) * 8);                                        \
    gll16(Bg + (size_t)(nt * 128 + row0) * 1024 + kb * 32 + cg0 * 8,           \
          Bs + (size_t)(wid * 64) * 8);                                        \
    gll16(Ag + (size_t)(mt * 128 + row1) * 1024 + kb * 32 + cg1 * 8,           \
          As + (size_t)(256 + wid * 64) * 8);                                  \
    gll16(Bg + (size_t)(nt * 128 + row1) * 1024 + kb * 32 + cg1 * 8,           \
          Bs + (size_t)(256 + wid * 64) * 8);                                  \
    __syncthreads();                                                           \
    s16x8 af[4], bf[4];                                                        \
    _Pragma("unroll") for (int mf = 0; mf < 4; ++mf) {                         \
      int rr = wr * 64 + mf * 16 + ln;                                         \
      af[mf] = *(const s16x8*)(As + rr * 32 + (g ^ ((rr >> 1) & 3)) * 8);      \
    }                                                                          \
    _Pragma("unroll") for (int nf = 0; nf < 4; ++nf) {                         \
      int rr = wc * 64 + nf * 16 + ln;                                         \
      bf[nf] = *(const s16x8*)(Bs + rr * 32 + (g ^ ((rr >> 1) & 3)) * 8);      \
    }                                                                          \
    _Pragma("unroll") for (int mf = 0; mf < 4; ++mf)                           \
      _Pragma("unroll") for (int nf = 0; nf < 4; ++nf)                         \
        acc[mf][nf] = MFMA16(af[mf], bf[nf], acc[mf][nf]);                     \
    __syncthreads();                                                           \
  }

// C = A @ W^T + bias.  z=0 -> Q (bf16), z=1 -> K (bf16), z=2 -> V stored transposed per head.
__global__ __launch_bounds__(256) void gemm_qkv_kernel(
    const unsigned short* __restrict__ qb, const unsigned short* __restrict__ kb16,
    const unsigned short* __restrict__ vb,
    const unsigned short* __restrict__ Wqb, const unsigned short* __restrict__ Wkb,
    const unsigned short* __restrict__ Wvb,
    const float* __restrict__ bq, const float* __restrict__ bk, const float* __restrict__ bv,
    unsigned short* __restrict__ Qo, unsigned short* __restrict__ Ko,
    unsigned short* __restrict__ Vto) {
  const int z = blockIdx.z;
  const unsigned short* Ag = (z == 0) ? qb : (z == 1) ? kb16 : vb;
  const unsigned short* Bg = (z == 0) ? Wqb : (z == 1) ? Wkb : Wvb;
  const float* bias = (z == 0) ? bq : (z == 1) ? bk : bv;
  GEMM_PROLOG();
  GEMM_KLOOP(Ag, Bg);
  if (z < 2) {
    unsigned short* out = (z == 0) ? Qo : Ko;
#pragma unroll
    for (int nf = 0; nf < 4; ++nf) {
      const int col = nt * 128 + wc * 64 + nf * 16 + ln;
      const float bb = bias[col];
#pragma unroll
      for (int mf = 0; mf < 4; ++mf) {
        const int rowb = mt * 128 + wr * 64 + mf * 16 + g * 4;
#pragma unroll
        for (int r = 0; r < 4; ++r)
          out[(size_t)(rowb + r) * 1024 + col] = f2bf(acc[mf][nf][r] + bb);
      }
    }
  } else {
#pragma unroll
    for (int nf = 0; nf < 4; ++nf) {
      const int col = nt * 128 + wc * 64 + nf * 16 + ln;
      const float bb = bias[col];
      const int hh = col >> 6, d = col & 63;
#pragma unroll
      for (int mf = 0; mf < 4; ++mf) {
        const int rowb = mt * 128 + wr * 64 + mf * 16 + g * 4;
#pragma unroll
        for (int r = 0; r < 4; ++r) {
          const int row = rowb + r, b = row >> 10, s = row & 1023;
          Vto[(((size_t)b * 16 + hh) * 64 + d) * 1024 + s] = f2bf(acc[mf][nf][r] + bb);
        }
      }
    }
  }
}

// x = ctx @ Wo^T + bo + q   (fp32 out, residual fused)
__global__ __launch_bounds__(256) void gemm_o_kernel(
    const unsigned short* __restrict__ ctx, const unsigned short* __restrict__ Wob,
    const float* __restrict__ bo, const float* __restrict__ qres,
    float* __restrict__ x) {
  GEMM_PROLOG();
  GEMM_KLOOP(ctx, Wob);
#pragma unroll
  for (int nf = 0; nf < 4; ++nf) {
    const int col = nt * 128 + wc * 64 + nf * 16 + ln;
    const float bb = bo[col];
#pragma unroll
    for (int mf = 0; mf < 4; ++mf) {
      const int rowb = mt * 128 + wr * 64 + mf * 16 + g * 4;
#pragma unroll
      for (int r = 0; r < 4; ++r) {
        const size_t idx = (size_t)(rowb + r) * 1024 + col;
        x[idx] = acc[mf][nf][r] + bb + qres[idx];
      }
    }
  }
}

// ---------------- fused attention: scores -> softmax -> att(out) -> PV ----------------
// grid (32 q-blocks, 64 b*h), 8 waves. Wave (wr,wc): scores rows wr*16..+16, cols wc*256..+256.
__global__ __launch_bounds__(512) void attn_kernel(
    const unsigned short* __restrict__ Q, const unsigned short* __restrict__ K,
    const unsigned short* __restrict__ Vt, unsigned short* __restrict__ ctx,
    float* __restrict__ att) {
  __shared__ unsigned short att_lds[32 * 1024];  // 64 KiB, XOR-swizzled (T2)
  float* red = (float*)att_lds;                  // aliased reduce buf (freed before att_lds writes)

  const int tid = threadIdx.x;
  const int lane = tid & 63, wid = tid >> 6;
  const int g = lane >> 4, ln = lane & 15;
  const int wc = wid & 3, wr = wid >> 2;
  const int qb = blockIdx.x;   // 0..31
  const int bh = blockIdx.y;   // 0..63
  const int b = bh >> 4, h = bh & 15;
  const int s0 = qb * 32;
  const int arow = b * 1024 + s0;

  // ---- QK^T: sc[nf] is 16x16 tile at cols wc*256+nf*16 ----
  s16x8 aQ0, aQ1;
  {
    const unsigned short* qp = Q + (size_t)(arow + wr * 16 + ln) * 1024 + h * 64 + g * 8;
    aQ0 = *(const s16x8*)qp;
    aQ1 = *(const s16x8*)(qp + 32);
  }
  f32x4 sc[16];
  { f32x4 z = {0.f, 0.f, 0.f, 0.f};
#pragma unroll
    for (int nf = 0; nf < 16; ++nf) sc[nf] = z; }
  const unsigned short* kbase = K + (size_t)(b * 1024) * 1024 + h * 64 + g * 8;
#pragma unroll
  for (int nf = 0; nf < 16; ++nf) {
    const unsigned short* kp = kbase + (size_t)(wc * 256 + nf * 16 + ln) * 1024;
    s16x8 b0 = *(const s16x8*)kp;
    s16x8 b1 = *(const s16x8*)(kp + 32);
    sc[nf] = MFMA16(aQ0, b0, sc[nf]);
    sc[nf] = MFMA16(aQ1, b1, sc[nf]);
  }

  // ---- softmax (rows local: 4g+r within 16-row group wr) ----
  float m[4], rsum[4];
#pragma unroll
  for (int r = 0; r < 4; ++r) {
    float v = sc[0][r];
#pragma unroll
    for (int nf = 1; nf < 16; ++nf) v = fmaxf(v, sc[nf][r]);
#pragma unroll
    for (int off = 1; off < 16; off <<= 1) v = fmaxf(v, __shfl_xor(v, off));
    m[r] = v;
  }
  if (ln == 0) {
#pragma unroll
    for (int r = 0; r < 4; ++r) red[(wr * 4 + wc) * 16 + g * 4 + r] = m[r];
  }
  __syncthreads();  // B1
#pragma unroll
  for (int r = 0; r < 4; ++r) {
    float v = red[(wr * 4 + 0) * 16 + g * 4 + r];
    v = fmaxf(v, red[(wr * 4 + 1) * 16 + g * 4 + r]);
    v = fmaxf(v, red[(wr * 4 + 2) * 16 + g * 4 + r]);
    v = fmaxf(v, red[(wr * 4 + 3) * 16 + g * 4 + r]);
    m[r] = v;
  }
  const float cexp = 0.18033688011112042f;  // log2(e)/8  (scale = sqrt(64))
#pragma unroll
  for (int r = 0; r < 4; ++r) rsum[r] = 0.f;
#pragma unroll
  for (int nf = 0; nf < 16; ++nf) {
#pragma unroll
    for (int r = 0; r < 4; ++r) {
      float p = __builtin_amdgcn_exp2f((sc[nf][r] - m[r]) * cexp);
      sc[nf][r] = p;
      rsum[r] += p;
    }
  }
#pragma unroll
  for (int r = 0; r < 4; ++r) {
    float v = rsum[r];
#pragma unroll
    for (int off = 1; off < 16; off <<= 1) v += __shfl_xor(v, off);
    rsum[r] = v;
  }
  if (ln == 0) {
#pragma unroll
    for (int r = 0; r < 4; ++r) red[128 + (wr * 4 + wc) * 16 + g * 4 + r] = rsum[r];
  }
  __syncthreads();  // B2
  float rinv[4];
#pragma unroll
  for (int r = 0; r < 4; ++r) {
    float v = red[128 + (wr * 4 + 0) * 16 + g * 4 + r] + red[128 + (wr * 4 + 1) * 16 + g * 4 + r] +
              red[128 + (wr * 4 + 2) * 16 + g * 4 + r] + red[128 + (wr * 4 + 3) * 16 + g * 4 + r];
    rinv[r] = __builtin_amdgcn_rcpf(v);
  }
  __syncthreads();  // B3: red region is about to be overwritten by att_lds

  // ---- write att (fp32 global) + bf16 swizzled LDS tile ----
  float* aout = att + ((size_t)bh * 1024 + s0) * 1024;
#pragma unroll
  for (int nf = 0; nf < 16; ++nf) {
    const int colt = wc * 256 + nf * 16 + ln;
#pragma unroll
    for (int r = 0; r < 4; ++r) {
      const int rowt = wr * 16 + g * 4 + r;
      const float a = sc[nf][r] * rinv[r];
      aout[(size_t)rowt * 1024 + colt] = a;
      const int off = (rowt * 2048 + colt * 2) ^ ((rowt & 7) << 4);
      *(unsigned short*)((char*)att_lds + off) = f2bf(a);
    }
  }
  __syncthreads();  // B4

  // ---- PV: wave (wr,wc) -> ctx tile rows wr*16, cols wc*16 of dv=64 ----
  f32x4 cacc = {0.f, 0.f, 0.f, 0.f};
  const unsigned short* vbase = Vt + ((size_t)bh * 64 + wc * 16 + ln) * 1024 + g * 8;
  const int row2 = wr * 16 + ln;
#pragma unroll 4
  for (int kk = 0; kk < 32; ++kk) {
    const int offa = (row2 * 2048 + kk * 64 + g * 16) ^ ((row2 & 7) << 4);
    s16x8 pa = *(const s16x8*)((const char*)att_lds + offa);
    s16x8 pb = *(const s16x8*)(vbase + kk * 32);
    cacc = MFMA16(pa, pb, cacc);
  }
  unsigned short* cp = ctx + (size_t)(arow + wr * 16 + g * 4) * 1024 + h * 64 + wc * 16 + ln;
#pragma unroll
  for (int r = 0; r < 4; ++r) cp[(size_t)r * 1024] = f2bf(cacc[r]);
}

// ---------------- LayerNorm ----------------
__global__ __launch_bounds__(256) void ln_kernel(
    const float* __restrict__ x, const float* __restrict__ gamma,
    const float* __restrict__ beta, float* __restrict__ y) {
  const int row = blockIdx.x, t = threadIdx.x;
  const int lane = t & 63, wid = t >> 6;
  const float* xr = x + (size_t)row * 1024 + t * 4;
  f32x4 v = *(const f32x4*)xr;
  float s = v[0] + v[1] + v[2] + v[3];
#pragma unroll
  for (int off = 1; off < 64; off <<= 1) s += __shfl_xor(s, off);
  __shared__ float red1[4], red2[4];
  if (lane == 0) red1[wid] = s;
  __syncthreads();
  const float mu = (red1[0] + red1[1] + red1[2] + red1[3]) * (1.0f / 1024.0f);
  const float d0 = v[0] - mu, d1 = v[1] - mu, d2 = v[2] - mu, d3 = v[3] - mu;
  float ss = d0 * d0 + d1 * d1 + d2 * d2 + d3 * d3;
#pragma unroll
  for (int off = 1; off < 64; off <<= 1) ss += __shfl_xor(ss, off);
  if (lane == 0) red2[wid] = ss;
  __syncthreads();
  const float var = (red2[0] + red2[1] + red2[2] + red2[3]) * (1.0f / 1024.0f);
  const float rstd = rsqrtf(var + 1e-5f);
  f32x4 gv = *(const f32x4*)(gamma + t * 4);
  f32x4 bv = *(const f32x4*)(beta + t * 4);
  f32x4 o;
  o[0] = d0 * rstd * gv[0] + bv[0];
  o[1] = d1 * rstd * gv[1] + bv[1];
  o[2] = d2 * rstd * gv[2] + bv[2];
  o[3] = d3 * rstd * gv[3] + bv[3];
  *(f32x4*)(y + (size_t)row * 1024 + t * 4) = o;
}

extern "C" void kernel_launch(void* const* d_in, const int* in_sizes, int n_in,
                              void* d_out, int out_size, void* d_ws, size_t ws_size,
                              hipStream_t stream) {
  const float* q  = (const float*)d_in[0];
  const float* k  = (const float*)d_in[1];
  const float* v  = (const float*)d_in[2];
  const float* Wq = (const float*)d_in[3];
  const float* bq = (const float*)d_in[4];
  const float* Wk = (const float*)d_in[5];
  const float* bk = (const float*)d_in[6];
  const float* Wv = (const float*)d_in[7];
  const float* bv = (const float*)d_in[8];
  const float* Wo = (const float*)d_in[9];
  const float* bo = (const float*)d_in[10];
  const float* gamma = (const float*)d_in[11];
  const float* beta  = (const float*)d_in[12];

  char* ws = (char*)d_ws;
  unsigned short* conv = (unsigned short*)ws;        // 16M bf16 elems = 32 MiB
  unsigned short* qb16 = conv;
  unsigned short* kb16 = conv + 4194304;
  unsigned short* vb16 = conv + 2 * 4194304;
  unsigned short* Wqb  = conv + 3 * 4194304;
  unsigned short* Wkb  = Wqb + 1048576;
  unsigned short* Wvb  = Wkb + 1048576;
  unsigned short* Wob  = Wvb + 1048576;
  unsigned short* Qb  = (unsigned short*)(ws + (32u << 20));  // 8 MiB
  unsigned short* Kb  = (unsigned short*)(ws + (40u << 20));  // 8 MiB
  unsigned short* Vtb = (unsigned short*)(ws + (48u << 20));  // 8 MiB (B,h,dv,S)
  unsigned short* ctx = (unsigned short*)(ws + (56u << 20));  // 8 MiB
  float* x = (float*)(ws + (32u << 20));  // 16 MiB, aliases Qb/Kb (dead after attn)

  float* y_out = (float*)d_out;
  float* att_out = y_out + 4194304;

  cvt_kernel<<<8192, 256, 0, stream>>>(q, k, v, Wq, Wk, Wv, Wo, conv);
  dim3 gq(8, 32, 3);
  gemm_qkv_kernel<<<gq, 256, 0, stream>>>(qb16, kb16, vb16, Wqb, Wkb, Wvb,
                                          bq, bk, bv, Qb, Kb, Vtb);
  dim3 ga(32, 64, 1);
  attn_kernel<<<ga, 512, 0, stream>>>(Qb, Kb, Vtb, ctx, att_out);
  dim3 go(8, 32, 1);
  gemm_o_kernel<<<go, 256, 0, stream>>>(ctx, Wob, bo, q, x);
  ln_kernel<<<4096, 256, 0, stream>>>(x, gamma, beta, y_out);
}